// Round 5
// baseline (94.564 us; speedup 1.0000x reference)
//
#include <hip/hip_runtime.h>
#include <hip/hip_bf16.h>

// NT-Xent loss, B=4096, D=128, N=8192, T=0.5, EPS=1e-8.
// loss = mean_k [ log( sum_j exp(2*cos(k,j)) - e^2 ) - 2*cos(k, partner(k)) ]
// Round 5: gemm at 4 waves/SIMD (TLP instead of manual double-buffer; ~110
// VGPRs, no spill), grid (128,8) = 4 blocks/CU balanced. Pair-fused prep.

#define NROWS 8192
#define BHALF 4096
#define DDIM  128

#define SCALE_A 2.8853900817779268f   // 2 * log2(e)
#define E2F     7.38905609893065f     // e^2
#define LN2F    0.6931471805599453f

typedef unsigned short u16;
typedef unsigned char  u8;
typedef __attribute__((ext_vector_type(8))) int   i32x8;
typedef __attribute__((ext_vector_type(4))) float f32x4;

static __device__ inline float dev_exp2(float x) {
#if __has_builtin(__builtin_amdgcn_exp2f)
    return __builtin_amdgcn_exp2f(x);
#else
    return exp2f(x);
#endif
}

static __device__ inline float dev_log2(float x) {
#if __has_builtin(__builtin_amdgcn_logf)
    return __builtin_amdgcn_logf(x);
#else
    return log2f(x);
#endif
}

#if !__has_builtin(__builtin_amdgcn_cvt_pk_fp8_f32)
#include <hip/hip_fp8.h>
#endif

// pack two floats to two OCP e4m3 bytes (low 16 bits)
static __device__ inline u16 pk_fp8(float x, float y) {
#if __has_builtin(__builtin_amdgcn_cvt_pk_fp8_f32)
    int v = __builtin_amdgcn_cvt_pk_fp8_f32(x, y, 0, false);
    return (u16)(v & 0xffff);
#else
    __hip_fp8_e4m3 a(x), b(y);
    return (u16)(a.__x | ((u16)b.__x << 8));
#endif
}

static __device__ inline i32x8 mk8(uint4 lo, uint4 hi) {
    i32x8 v;
    v[0] = (int)lo.x; v[1] = (int)lo.y; v[2] = (int)lo.z; v[3] = (int)lo.w;
    v[4] = (int)hi.x; v[5] = (int)hi.y; v[6] = (int)hi.z; v[7] = (int)hi.w;
    return v;
}

// ---------------------------------------------------------------------------
// zn_t layout: row r -> group g = r>>4, rr = r&15. 16B chunk c (elements
// k in [16c,16c+16)) stored at byte offset g*2048 + c*256 + rr*16.
// A 16-lane MFMA fragment load (rows = l15, k-chunk fixed) is then a fully
// coalesced 256B run with operand bytes in plain k order.
// ---------------------------------------------------------------------------
static __device__ inline int znt_addr(int row, int lane) {
    // elements k = 2*lane, 2*lane+1
    return ((row >> 4) << 11) + ((lane >> 3) << 8) + ((row & 15) << 4) + ((lane & 7) << 1);
}

// ---------------------------------------------------------------------------
// Kernel 1: one wave per (zi[r], zj[r]) PAIR — cos is symmetric, so
// pos[r] == pos[r+B]; each pair read once. Writes fp8 rows for both halves
// (znA scaled by 2*log2e, znB unit), fp32 pos, zeroes rowsum.
// ---------------------------------------------------------------------------
__global__ __launch_bounds__(256) void prep_kernel(
    const float* __restrict__ zi, const float* __restrict__ zj,
    u8* __restrict__ znA, u8* __restrict__ znB,
    float* __restrict__ pos, float* __restrict__ rowsum)
{
    const int pair = blockIdx.x * 4 + (threadIdx.x >> 6);   // 0..4095
    const int lane = threadIdx.x & 63;

    float2 a = *(const float2*)(zi + (size_t)pair * DDIM + lane * 2);
    float2 b = *(const float2*)(zj + (size_t)pair * DDIM + lane * 2);

    float ss = a.x * a.x + a.y * a.y;
    float sp = b.x * b.x + b.y * b.y;
    float dp = a.x * b.x + a.y * b.y;
    #pragma unroll
    for (int o = 32; o > 0; o >>= 1) {
        ss += __shfl_xor(ss, o);
        sp += __shfl_xor(sp, o);
        dp += __shfl_xor(dp, o);
    }

    float invA = 1.0f / fmaxf(sqrtf(ss), 1e-8f);
    float invB = 1.0f / fmaxf(sqrtf(sp), 1e-8f);

    const int a1 = znt_addr(pair, lane);            // row k1 = pair
    const int a2 = znt_addr(pair + BHALF, lane);    // row k2 = pair + B

    *(u16*)(znA + a1) = pk_fp8(a.x * invA * SCALE_A, a.y * invA * SCALE_A);
    *(u16*)(znB + a1) = pk_fp8(a.x * invA,           a.y * invA);
    *(u16*)(znA + a2) = pk_fp8(b.x * invB * SCALE_A, b.y * invB * SCALE_A);
    *(u16*)(znB + a2) = pk_fp8(b.x * invB,           b.y * invB);

    if (lane == 0) {
        float p = 2.0f * dp * invA * invB;
        pos[pair]            = p;
        pos[pair + BHALF]    = p;
        rowsum[pair]         = 0.0f;
        rowsum[pair + BHALF] = 0.0f;
    }
}

// ---------------------------------------------------------------------------
// Kernel 2: no-LDS MFMA sim + exp2 + row-sum. Grid (128, 8) x 256 thr
// = 1024 blocks = exactly 4 blocks/CU at __launch_bounds__(256,4).
// Each wave: 64 rows x 256 cols (4 tiles of 64 cols), K=128 in one
// mfma_scale_f32_16x16x128_f8f6f4 per 16x16 frag. Single-buffered B frags
// (~110 VGPRs, no spill); TLP across 4 waves/SIMD hides load latency.
// No __syncthreads, no fence.
// ---------------------------------------------------------------------------
__global__ __launch_bounds__(256, 4) void gemm_lse_kernel(
    const u8* __restrict__ znA, const u8* __restrict__ znB,
    float* __restrict__ rowsum)
{
    const int wave = threadIdx.x >> 6;
    const int lane = threadIdx.x & 63;
    const int l15  = lane & 15;
    const int l4   = lane >> 4;

    const int rowbase = blockIdx.x * 64;                  // 128 row-blocks
    const int colgrp0 = (blockIdx.y * 4 + wave) * 16;     // 32 col strips of 256
    const int laneoff = (l4 * 2) * 256 + l15 * 16;        // chunk 2*l4, row l15

    // A fragments: loaded once, reused across 4 col-tiles
    i32x8 a[4];
    #pragma unroll
    for (int r = 0; r < 4; ++r) {
        const u8* p = znA + (size_t)((rowbase >> 4) + r) * 2048 + laneoff;
        a[r] = mk8(*(const uint4*)(p), *(const uint4*)(p + 256));
    }

    float psum[16];
    #pragma unroll
    for (int i = 0; i < 16; ++i) psum[i] = 0.0f;

    const f32x4 zero = {0.0f, 0.0f, 0.0f, 0.0f};

    #pragma unroll 1
    for (int ct = 0; ct < 4; ++ct) {
        i32x8 b[4];
        #pragma unroll
        for (int c = 0; c < 4; ++c) {
            const u8* p = znB + (size_t)(colgrp0 + ct * 4 + c) * 2048 + laneoff;
            b[c] = mk8(*(const uint4*)(p), *(const uint4*)(p + 256));
        }

        #pragma unroll
        for (int r = 0; r < 4; ++r) {
            f32x4 t0 = __builtin_amdgcn_mfma_scale_f32_16x16x128_f8f6f4(
                a[r], b[0], zero, 0, 0, 0, 0x7f7f7f7f, 0, 0x7f7f7f7f);
            f32x4 t1 = __builtin_amdgcn_mfma_scale_f32_16x16x128_f8f6f4(
                a[r], b[1], zero, 0, 0, 0, 0x7f7f7f7f, 0, 0x7f7f7f7f);
            f32x4 t2 = __builtin_amdgcn_mfma_scale_f32_16x16x128_f8f6f4(
                a[r], b[2], zero, 0, 0, 0, 0x7f7f7f7f, 0, 0x7f7f7f7f);
            f32x4 t3 = __builtin_amdgcn_mfma_scale_f32_16x16x128_f8f6f4(
                a[r], b[3], zero, 0, 0, 0, 0x7f7f7f7f, 0, 0x7f7f7f7f);
            #pragma unroll
            for (int i = 0; i < 4; ++i)
                psum[r * 4 + i] += dev_exp2(t0[i]) + dev_exp2(t1[i])
                                 + dev_exp2(t2[i]) + dev_exp2(t3[i]);
        }
    }

    // reduce across the 16 column-lanes (l15)
    #pragma unroll
    for (int i = 0; i < 16; ++i) {
        float v = psum[i];
        v += __shfl_xor(v, 1);
        v += __shfl_xor(v, 2);
        v += __shfl_xor(v, 4);
        v += __shfl_xor(v, 8);
        psum[i] = v;
    }

    if (l15 == 0) {
        #pragma unroll
        for (int r = 0; r < 4; ++r)
            #pragma unroll
            for (int i = 0; i < 4; ++i)
                atomicAdd(&rowsum[rowbase + r * 16 + l4 * 4 + i],
                          psum[r * 4 + i]);
    }
}

// ---------------------------------------------------------------------------
// Kernel 3: loss = mean( log(rowsum - e^2) - pos )
// ---------------------------------------------------------------------------
__global__ __launch_bounds__(256) void final_kernel(
    const float* __restrict__ rowsum, const float* __restrict__ pos,
    float* __restrict__ out)
{
    const int t = threadIdx.x;
    float s = 0.0f;
    #pragma unroll
    for (int k = t; k < NROWS; k += 256)
        s += dev_log2(rowsum[k] - E2F) * LN2F - pos[k];

    #pragma unroll
    for (int o = 32; o > 0; o >>= 1) s += __shfl_xor(s, o);

    __shared__ float red[4];
    if ((t & 63) == 0) red[t >> 6] = s;
    __syncthreads();
    if (t == 0) out[0] = (red[0] + red[1] + red[2] + red[3]) * (1.0f / (float)NROWS);
}

// ---------------------------------------------------------------------------
extern "C" void kernel_launch(void* const* d_in, const int* in_sizes, int n_in,
                              void* d_out, int out_size, void* d_ws, size_t ws_size,
                              hipStream_t stream)
{
    const float* zi = (const float*)d_in[0];
    const float* zj = (const float*)d_in[1];
    float* out = (float*)d_out;

    char* ws = (char*)d_ws;
    u8*    znA    = (u8*)(ws);                           // 1 MB
    u8*    znB    = (u8*)(ws + (1u << 20));              // 1 MB
    float* rowsum = (float*)(ws + (2u << 20));           // 32 KB
    float* pos    = (float*)(ws + (2u << 20) + 32768);   // 32 KB

    prep_kernel<<<BHALF / 4, 256, 0, stream>>>(zi, zj, znA, znB, pos, rowsum);
    gemm_lse_kernel<<<dim3(128, 8), 256, 0, stream>>>(znA, znB, rowsum);
    final_kernel<<<1, 256, 0, stream>>>(rowsum, pos, out);
}

// Round 6
// 80.372 us; speedup vs baseline: 1.1766x; 1.1766x over previous
//
#include <hip/hip_runtime.h>
#include <hip/hip_bf16.h>

// NT-Xent loss, B=4096, D=128, N=8192, T=0.5, EPS=1e-8.
// loss = mean_k [ log( sum_j exp(2*cos(k,j)) - e^2 ) - 2*cos(k, partner(k)) ]
// Round 6: gemm at 3 waves/SIMD — single-buffered B frags (~130 regs, fits
// the 170-reg cap of (256,3); measured twice that 128-reg cap spills).
// Grid (128,8). Pair-fused prep. Separate 1-block final kernel.

#define NROWS 8192
#define BHALF 4096
#define DDIM  128

#define SCALE_A 2.8853900817779268f   // 2 * log2(e)
#define E2F     7.38905609893065f     // e^2
#define LN2F    0.6931471805599453f

typedef unsigned short u16;
typedef unsigned char  u8;
typedef __attribute__((ext_vector_type(8))) int   i32x8;
typedef __attribute__((ext_vector_type(4))) float f32x4;

static __device__ inline float dev_exp2(float x) {
#if __has_builtin(__builtin_amdgcn_exp2f)
    return __builtin_amdgcn_exp2f(x);
#else
    return exp2f(x);
#endif
}

static __device__ inline float dev_log2(float x) {
#if __has_builtin(__builtin_amdgcn_logf)
    return __builtin_amdgcn_logf(x);
#else
    return log2f(x);
#endif
}

#if !__has_builtin(__builtin_amdgcn_cvt_pk_fp8_f32)
#include <hip/hip_fp8.h>
#endif

// pack two floats to two OCP e4m3 bytes (low 16 bits)
static __device__ inline u16 pk_fp8(float x, float y) {
#if __has_builtin(__builtin_amdgcn_cvt_pk_fp8_f32)
    int v = __builtin_amdgcn_cvt_pk_fp8_f32(x, y, 0, false);
    return (u16)(v & 0xffff);
#else
    __hip_fp8_e4m3 a(x), b(y);
    return (u16)(a.__x | ((u16)b.__x << 8));
#endif
}

static __device__ inline i32x8 mk8(uint4 lo, uint4 hi) {
    i32x8 v;
    v[0] = (int)lo.x; v[1] = (int)lo.y; v[2] = (int)lo.z; v[3] = (int)lo.w;
    v[4] = (int)hi.x; v[5] = (int)hi.y; v[6] = (int)hi.z; v[7] = (int)hi.w;
    return v;
}

// ---------------------------------------------------------------------------
// zn_t layout: row r -> group g = r>>4, rr = r&15. 16B chunk c (elements
// k in [16c,16c+16)) stored at byte offset g*2048 + c*256 + rr*16.
// A 16-lane MFMA fragment load (rows = l15, k-chunk fixed) is then a fully
// coalesced 256B run with operand bytes in plain k order.
// ---------------------------------------------------------------------------
static __device__ inline int znt_addr(int row, int lane) {
    // elements k = 2*lane, 2*lane+1
    return ((row >> 4) << 11) + ((lane >> 3) << 8) + ((row & 15) << 4) + ((lane & 7) << 1);
}

// ---------------------------------------------------------------------------
// Kernel 1: one wave per (zi[r], zj[r]) PAIR — cos is symmetric, so
// pos[r] == pos[r+B]; each pair read once. Writes fp8 rows for both halves
// (znA scaled by 2*log2e, znB unit), fp32 pos, zeroes rowsum.
// ---------------------------------------------------------------------------
__global__ __launch_bounds__(256) void prep_kernel(
    const float* __restrict__ zi, const float* __restrict__ zj,
    u8* __restrict__ znA, u8* __restrict__ znB,
    float* __restrict__ pos, float* __restrict__ rowsum)
{
    const int pair = blockIdx.x * 4 + (threadIdx.x >> 6);   // 0..4095
    const int lane = threadIdx.x & 63;

    float2 a = *(const float2*)(zi + (size_t)pair * DDIM + lane * 2);
    float2 b = *(const float2*)(zj + (size_t)pair * DDIM + lane * 2);

    float ss = a.x * a.x + a.y * a.y;
    float sp = b.x * b.x + b.y * b.y;
    float dp = a.x * b.x + a.y * b.y;
    #pragma unroll
    for (int o = 32; o > 0; o >>= 1) {
        ss += __shfl_xor(ss, o);
        sp += __shfl_xor(sp, o);
        dp += __shfl_xor(dp, o);
    }

    float invA = 1.0f / fmaxf(sqrtf(ss), 1e-8f);
    float invB = 1.0f / fmaxf(sqrtf(sp), 1e-8f);

    const int a1 = znt_addr(pair, lane);            // row k1 = pair
    const int a2 = znt_addr(pair + BHALF, lane);    // row k2 = pair + B

    *(u16*)(znA + a1) = pk_fp8(a.x * invA * SCALE_A, a.y * invA * SCALE_A);
    *(u16*)(znB + a1) = pk_fp8(a.x * invA,           a.y * invA);
    *(u16*)(znA + a2) = pk_fp8(b.x * invB * SCALE_A, b.y * invB * SCALE_A);
    *(u16*)(znB + a2) = pk_fp8(b.x * invB,           b.y * invB);

    if (lane == 0) {
        float p = 2.0f * dp * invA * invB;
        pos[pair]            = p;
        pos[pair + BHALF]    = p;
        rowsum[pair]         = 0.0f;
        rowsum[pair + BHALF] = 0.0f;
    }
}

// ---------------------------------------------------------------------------
// Kernel 2: no-LDS MFMA sim + exp2 + row-sum. Grid (128, 8) x 256 thr.
// __launch_bounds__(256,3): 170-reg budget — single-buffered B frags fit
// (~130 regs). 3 waves/SIMD TLP hides L2 load latency. Each wave: 64 rows x
// 256 cols (4 tiles of 64 cols), K=128 in one mfma_scale per 16x16 frag.
// No __syncthreads, no fence (both measured harmful: R3 fence storm).
// ---------------------------------------------------------------------------
__global__ __launch_bounds__(256, 3) void gemm_lse_kernel(
    const u8* __restrict__ znA, const u8* __restrict__ znB,
    float* __restrict__ rowsum)
{
    const int wave = threadIdx.x >> 6;
    const int lane = threadIdx.x & 63;
    const int l15  = lane & 15;
    const int l4   = lane >> 4;

    const int rowbase = blockIdx.x * 64;                  // 128 row-blocks
    const int colgrp0 = (blockIdx.y * 4 + wave) * 16;     // 32 col strips of 256
    const int laneoff = (l4 * 2) * 256 + l15 * 16;        // chunk 2*l4, row l15

    // A fragments: loaded once, reused across 4 col-tiles
    i32x8 a[4];
    #pragma unroll
    for (int r = 0; r < 4; ++r) {
        const u8* p = znA + (size_t)((rowbase >> 4) + r) * 2048 + laneoff;
        a[r] = mk8(*(const uint4*)(p), *(const uint4*)(p + 256));
    }

    float psum[16];
    #pragma unroll
    for (int i = 0; i < 16; ++i) psum[i] = 0.0f;

    const f32x4 zero = {0.0f, 0.0f, 0.0f, 0.0f};

    #pragma unroll 1
    for (int ct = 0; ct < 4; ++ct) {
        i32x8 b[4];
        #pragma unroll
        for (int c = 0; c < 4; ++c) {
            const u8* p = znB + (size_t)(colgrp0 + ct * 4 + c) * 2048 + laneoff;
            b[c] = mk8(*(const uint4*)(p), *(const uint4*)(p + 256));
        }

        #pragma unroll
        for (int r = 0; r < 4; ++r) {
            f32x4 t0 = __builtin_amdgcn_mfma_scale_f32_16x16x128_f8f6f4(
                a[r], b[0], zero, 0, 0, 0, 0x7f7f7f7f, 0, 0x7f7f7f7f);
            f32x4 t1 = __builtin_amdgcn_mfma_scale_f32_16x16x128_f8f6f4(
                a[r], b[1], zero, 0, 0, 0, 0x7f7f7f7f, 0, 0x7f7f7f7f);
            f32x4 t2 = __builtin_amdgcn_mfma_scale_f32_16x16x128_f8f6f4(
                a[r], b[2], zero, 0, 0, 0, 0x7f7f7f7f, 0, 0x7f7f7f7f);
            f32x4 t3 = __builtin_amdgcn_mfma_scale_f32_16x16x128_f8f6f4(
                a[r], b[3], zero, 0, 0, 0, 0x7f7f7f7f, 0, 0x7f7f7f7f);
            #pragma unroll
            for (int i = 0; i < 4; ++i)
                psum[r * 4 + i] += dev_exp2(t0[i]) + dev_exp2(t1[i])
                                 + dev_exp2(t2[i]) + dev_exp2(t3[i]);
        }
    }

    // reduce across the 16 column-lanes (l15)
    #pragma unroll
    for (int i = 0; i < 16; ++i) {
        float v = psum[i];
        v += __shfl_xor(v, 1);
        v += __shfl_xor(v, 2);
        v += __shfl_xor(v, 4);
        v += __shfl_xor(v, 8);
        psum[i] = v;
    }

    if (l15 == 0) {
        #pragma unroll
        for (int r = 0; r < 4; ++r)
            #pragma unroll
            for (int i = 0; i < 4; ++i)
                atomicAdd(&rowsum[rowbase + r * 16 + l4 * 4 + i],
                          psum[r * 4 + i]);
    }
}

// ---------------------------------------------------------------------------
// Kernel 3: loss = mean( log(rowsum - e^2) - pos )
// ---------------------------------------------------------------------------
__global__ __launch_bounds__(256) void final_kernel(
    const float* __restrict__ rowsum, const float* __restrict__ pos,
    float* __restrict__ out)
{
    const int t = threadIdx.x;
    float s = 0.0f;
    #pragma unroll
    for (int k = t; k < NROWS; k += 256)
        s += dev_log2(rowsum[k] - E2F) * LN2F - pos[k];

    #pragma unroll
    for (int o = 32; o > 0; o >>= 1) s += __shfl_xor(s, o);

    __shared__ float red[4];
    if ((t & 63) == 0) red[t >> 6] = s;
    __syncthreads();
    if (t == 0) out[0] = (red[0] + red[1] + red[2] + red[3]) * (1.0f / (float)NROWS);
}

// ---------------------------------------------------------------------------
extern "C" void kernel_launch(void* const* d_in, const int* in_sizes, int n_in,
                              void* d_out, int out_size, void* d_ws, size_t ws_size,
                              hipStream_t stream)
{
    const float* zi = (const float*)d_in[0];
    const float* zj = (const float*)d_in[1];
    float* out = (float*)d_out;

    char* ws = (char*)d_ws;
    u8*    znA    = (u8*)(ws);                           // 1 MB
    u8*    znB    = (u8*)(ws + (1u << 20));              // 1 MB
    float* rowsum = (float*)(ws + (2u << 20));           // 32 KB
    float* pos    = (float*)(ws + (2u << 20) + 32768);   // 32 KB

    prep_kernel<<<BHALF / 4, 256, 0, stream>>>(zi, zj, znA, znB, pos, rowsum);
    gemm_lse_kernel<<<dim3(128, 8), 256, 0, stream>>>(znA, znB, rowsum);
    final_kernel<<<1, 256, 0, stream>>>(rowsum, pos, out);
}